// Round 4
// baseline (1809.498 us; speedup 1.0000x reference)
//
#include <hip/hip_runtime.h>

typedef unsigned short u16;
typedef unsigned int u32;
typedef __attribute__((ext_vector_type(8))) __bf16 bf16x8;
typedef __attribute__((ext_vector_type(4))) float f32x4;

union U8 {
  bf16x8 b;
  uint2 u2[2];
  uint4 u4;
  u16 us[8];
};

__device__ __forceinline__ u16 f2bf(float f) {
  u32 x = __float_as_uint(f);
  x += 0x7FFFu + ((x >> 16) & 1u);
  return (u16)(x >> 16);
}
__device__ __forceinline__ float bf2f(u16 u) {
  return __uint_as_float(((u32)u) << 16);
}

// async global->LDS, 16B per lane. LDS dest = wave-uniform base + lane*16.
#define GLOAD16(gp, lp)                                                          \
  __builtin_amdgcn_global_load_lds(                                              \
      (const __attribute__((address_space(1))) unsigned int*)(const void*)(gp),  \
      (__attribute__((address_space(3))) unsigned int*)(void*)(lp), 16, 0, 0)

// ---------------- f32 -> bf16 convert: x, W_qkv, W_out in one launch ----------------
__global__ void k_convert_all(const float* __restrict__ x, const float* __restrict__ wq,
                              const float* __restrict__ wo, u16* __restrict__ xb,
                              u16* __restrict__ wqb, u16* __restrict__ wob) {
  const int NX = 1048576, NQ = 786432, NO = 262144;  // float4 counts
  int idx = blockIdx.x * blockDim.x + threadIdx.x;
  int stride = gridDim.x * blockDim.x;
  for (int i = idx; i < NX + NQ + NO; i += stride) {
    const float4* s;
    ushort4* d;
    int k;
    if (i < NX) { s = (const float4*)x; d = (ushort4*)xb; k = i; }
    else if (i < NX + NQ) { s = (const float4*)wq; d = (ushort4*)wqb; k = i - NX; }
    else { s = (const float4*)wo; d = (ushort4*)wob; k = i - NX - NQ; }
    float4 v = s[k];
    ushort4 o;
    o.x = f2bf(v.x); o.y = f2bf(v.y); o.z = f2bf(v.z); o.w = f2bf(v.w);
    d[k] = o;
  }
}

// ---------------- rel projection -> MFMA-fragment-ordered bf16 ----------------
// out[tile(b,h,nt,mt)*1024 + c*256 + lane*4 + j]
//   = rel(b, h, n = nt*16 + 4*(lane>>4) + j, m = mt*64 + c*16 + (lane&15))
// tile = ((b*16+h)*32 + nt)*8 + mt.
// Wave (= fixed c) stores 64 lanes x 8B CONTIGUOUS per h (512B dense lines).
__global__ __launch_bounds__(256, 3) void k_rel(const float* __restrict__ rb,
                                                const float* __restrict__ Wr,
                                                const float* __restrict__ br,
                                                u16* __restrict__ out) {
  __shared__ float Wl[16][32];
  __shared__ float bl[16];
  int t = threadIdx.x;
  ((float*)Wl)[t] = Wr[t];
  ((float*)Wl)[t + 256] = Wr[t + 256];
  if (t < 16) bl[t] = br[t];
  __syncthreads();

  const int c = t >> 6, lane = t & 63, g = lane >> 4, i16 = lane & 15;
  const int mt = blockIdx.x, nt = blockIdx.y, b = blockIdx.z;

  u32 pk[16][2];
#pragma unroll
  for (int h = 0; h < 16; ++h) pk[h][0] = pk[h][1] = 0u;

#pragma unroll
  for (int j = 0; j < 4; ++j) {
    size_t prow = ((size_t)(b * 512 + nt * 16 + 4 * g + j)) * 512 + mt * 64 + c * 16 + i16;
    const float4* rp = (const float4*)(rb + prow * 32);
    float4 r4[8];
#pragma unroll
    for (int q = 0; q < 8; ++q) r4[q] = rp[q];
#pragma unroll
    for (int h = 0; h < 16; ++h) {
      float acc = bl[h];
      const float* w = Wl[h];
#pragma unroll
      for (int q = 0; q < 8; ++q) {
        acc += r4[q].x * w[4 * q + 0] + r4[q].y * w[4 * q + 1] +
               r4[q].z * w[4 * q + 2] + r4[q].w * w[4 * q + 3];
      }
      pk[h][j >> 1] |= (u32)f2bf(acc) << (16 * (j & 1));
    }
  }

#pragma unroll
  for (int h = 0; h < 16; ++h) {
    uint2 w;
    w.x = pk[h][0];
    w.y = pk[h][1];
    size_t o = (((size_t)(b * 16 + h) * 32 + nt) * 8 + mt) * 1024 + c * 256 + lane * 4;
    *(uint2*)(out + o) = w;
  }
}

// ---------------- GEMM: C(M x N) = A(M x K) * W(N x K)^T + bias ----------------
// m97-style: 128x128 tile, BK=64, global_load_lds(16B) staging into linear LDS,
// both-sides XOR swizzle (global source chunk ^= r&7; ds_read chunk ^= row&7).
// MODE 0: qkv -> scatter bf16 into Q,K,V [b][h][n][d]
// MODE 1: out -> f32 C row-major with bias
template <int MODE>
__global__ __launch_bounds__(256) void k_gemm(const u16* __restrict__ A,
                                              const u16* __restrict__ Bm,
                                              const float* __restrict__ bias,
                                              u16* __restrict__ Qo, u16* __restrict__ Ko,
                                              u16* __restrict__ Vo, float* __restrict__ Co,
                                              int K) {
  __shared__ u16 Al[128 * 64];
  __shared__ u16 Bl[128 * 64];
  const int t = threadIdx.x;
  const int lane = t & 63, wid = t >> 6;
  const int g = lane >> 4, i16 = lane & 15;
  const int wm = wid >> 1, wn = wid & 1;
  const int bm = blockIdx.y, bn = blockIdx.x;

  f32x4 zero = {0.f, 0.f, 0.f, 0.f};
  f32x4 acc[4][4];
#pragma unroll
  for (int mi = 0; mi < 4; ++mi)
#pragma unroll
    for (int ni = 0; ni < 4; ++ni) acc[mi][ni] = zero;

  int srow[4], sgc[4];
#pragma unroll
  for (int i = 0; i < 4; ++i) {
    int ch = wid * 256 + i * 64 + lane;
    int r = ch >> 3, cs = ch & 7;
    srow[i] = r;
    sgc[i] = cs ^ (r & 7);
  }

  for (int k0 = 0; k0 < K; k0 += 64) {
    __syncthreads();
#pragma unroll
    for (int i = 0; i < 4; ++i) {
      const u16* ga = A + (size_t)(bm * 128 + srow[i]) * K + k0 + sgc[i] * 8;
      const u16* gb = Bm + (size_t)(bn * 128 + srow[i]) * K + k0 + sgc[i] * 8;
      GLOAD16(ga, Al + (size_t)(wid * 256 + i * 64) * 8);
      GLOAD16(gb, Bl + (size_t)(wid * 256 + i * 64) * 8);
    }
    __syncthreads();

#pragma unroll
    for (int kk = 0; kk < 2; ++kk) {
      U8 af[4], bfr[4];
#pragma unroll
      for (int mi = 0; mi < 4; ++mi) {
        int row = wm * 64 + mi * 16 + i16;
        int ch = (g + 4 * kk) ^ (row & 7);
        af[mi].u4 = *(const uint4*)(Al + row * 64 + ch * 8);
      }
#pragma unroll
      for (int ni = 0; ni < 4; ++ni) {
        int row = wn * 64 + ni * 16 + i16;
        int ch = (g + 4 * kk) ^ (row & 7);
        bfr[ni].u4 = *(const uint4*)(Bl + row * 64 + ch * 8);
      }
#pragma unroll
      for (int mi = 0; mi < 4; ++mi)
#pragma unroll
        for (int ni = 0; ni < 4; ++ni)
          acc[mi][ni] = __builtin_amdgcn_mfma_f32_16x16x32_bf16(af[mi].b, bfr[ni].b,
                                                                acc[mi][ni], 0, 0, 0);
    }
  }

#pragma unroll
  for (int mi = 0; mi < 4; ++mi) {
#pragma unroll
    for (int ni = 0; ni < 4; ++ni) {
      int colb = bn * 128 + wn * 64 + ni * 16;
      int col = colb + i16;
#pragma unroll
      for (int j = 0; j < 4; ++j) {
        int row = bm * 128 + wm * 64 + mi * 16 + 4 * g + j;
        float v = acc[mi][ni][j] + bias[col];
        if (MODE == 0) {
          int tt = col >> 10;
          int h = (col >> 6) & 15;
          int d = col & 63;
          int b = row >> 9;
          int n = row & 511;
          u16* dst = (tt == 0) ? Qo : ((tt == 1) ? Ko : Vo);
          dst[((size_t)(b * 16 + h) * 512 + n) * 64 + d] = f2bf(v);
        } else {
          Co[(size_t)row * 1024 + col] = v;
        }
      }
    }
  }
}

// ---------------- V transpose: [bh][n][d] -> [bh][d][n] ----------------
__global__ __launch_bounds__(256) void k_vt(const u16* __restrict__ V, u16* __restrict__ Vt) {
  __shared__ u16 Tl[64][72];
  const int t = threadIdx.x;
  const int n0 = blockIdx.x * 64;
  const size_t bh = blockIdx.y;
#pragma unroll
  for (int i = 0; i < 2; ++i) {
    int c = i * 256 + t;
    int r = c >> 3, c8 = (c & 7) * 8;
    U8 v;
    v.u4 = *(const uint4*)(V + (bh * 512 + n0 + r) * 64 + c8);
    *(uint2*)&Tl[r][c8] = v.u2[0];
    *(uint2*)&Tl[r][c8 + 4] = v.u2[1];
  }
  __syncthreads();
#pragma unroll
  for (int i = 0; i < 2; ++i) {
    int c = i * 256 + t;
    int d = c >> 3, n8 = (c & 7) * 8;
    U8 o;
#pragma unroll
    for (int j = 0; j < 8; ++j) o.us[j] = Tl[n8 + j][d];
    *(uint4*)(Vt + (bh * 64 + d) * 512 + n0 + n8) = o.u4;
  }
}

// ---------------- fused attention: softmax(Q K^T * scale + rel) V ----------------
// grid (qt=8, h=16, b=8), 256 threads = 4 waves, each wave owns 16 q-rows.
// K/Vt double-buffered via global_load_lds, prefetch issued before compute.
// rel read as 4x uint2 per thread per tile (dense fragment-ordered layout).
__global__ __launch_bounds__(256) void k_attn(const u16* __restrict__ Q,
                                              const u16* __restrict__ Kb,
                                              const u16* __restrict__ Vtb,
                                              const u16* __restrict__ Rel,
                                              u16* __restrict__ Out) {
  __shared__ u16 Kl[2][64 * 64];
  __shared__ u16 Vl[2][64 * 64];
  __shared__ u16 Pl[4][16 * 68];

  const int qt = blockIdx.x, h = blockIdx.y, b = blockIdx.z;
  const int t = threadIdx.x, lane = t & 63, wid = t >> 6;
  const int g = lane >> 4, i16 = lane & 15;
  const size_t bh = (size_t)(b * 16 + h);

  // Q fragments (held in registers for entire kernel)
  const u16* Qg = Q + (bh * 512 + qt * 64 + wid * 16 + i16) * 64;
  U8 qf[2];
  qf[0].u4 = *(const uint4*)(Qg + 8 * g);
  qf[1].u4 = *(const uint4*)(Qg + 8 * g + 32);

  float m_run[4], l_run[4];
  f32x4 zero = {0.f, 0.f, 0.f, 0.f};
  f32x4 acc[4];
#pragma unroll
  for (int c = 0; c < 4; ++c) acc[c] = zero;
#pragma unroll
  for (int j = 0; j < 4; ++j) { m_run[j] = -1e30f; l_run[j] = 0.f; }

  int srow[2], sgc[2];
#pragma unroll
  for (int i = 0; i < 2; ++i) {
    int ch = wid * 128 + i * 64 + lane;
    int r = ch >> 3, cs = ch & 7;
    srow[i] = r;
    sgc[i] = cs ^ (r & 7);
  }

  const u16* Kg0 = Kb + bh * 512 * 64;
  const u16* Vg0 = Vtb + bh * 64 * 512;
  // fragment-ordered rel: tile(b,h, nt=qt*4+wid, mt=it)*1024 + c*256 + lane*4 + j
  const u16* Rg = Rel + ((bh * 32 + qt * 4 + wid) * 8) * 1024 + lane * 4;

#define STAGE(buf, m0)                                                                  \
  do {                                                                                  \
    _Pragma("unroll") for (int i = 0; i < 2; ++i) {                                     \
      GLOAD16(Kg0 + (size_t)((m0) + srow[i]) * 64 + sgc[i] * 8,                         \
              &Kl[buf][(size_t)(wid * 128 + i * 64) * 8]);                              \
      GLOAD16(Vg0 + (size_t)srow[i] * 512 + (m0) + sgc[i] * 8,                          \
              &Vl[buf][(size_t)(wid * 128 + i * 64) * 8]);                              \
    }                                                                                   \
  } while (0)

  STAGE(0, 0);
  __syncthreads();

  for (int it = 0; it < 8; ++it) {
    const int buf = it & 1;
    if (it < 7) STAGE(buf ^ 1, it * 64 + 64);

    // rel fragments: 4 x uint2 (dense per wave), in flight under QK^T
    uint2 rl[4];
#pragma unroll
    for (int c = 0; c < 4; ++c) rl[c] = *(const uint2*)(Rg + it * 1024 + c * 256);

    // S = Q K^T  (per wave: 16 x 64)
    f32x4 s[4];
#pragma unroll
    for (int c = 0; c < 4; ++c) s[c] = zero;
    __builtin_amdgcn_s_setprio(1);
#pragma unroll
    for (int c = 0; c < 4; ++c) {
#pragma unroll
      for (int kk = 0; kk < 2; ++kk) {
        int row = c * 16 + i16;
        int ch = (g + 4 * kk) ^ (row & 7);
        U8 kf;
        kf.u4 = *(const uint4*)(&Kl[buf][row * 64 + ch * 8]);
        s[c] = __builtin_amdgcn_mfma_f32_16x16x32_bf16(qf[kk].b, kf.b, s[c], 0, 0, 0);
      }
    }
    __builtin_amdgcn_s_setprio(0);

    // scale + rel bias
#pragma unroll
    for (int c = 0; c < 4; ++c) {
      const u16* rc = (const u16*)&rl[c];
#pragma unroll
      for (int j = 0; j < 4; ++j) s[c][j] = s[c][j] * 0.125f + bf2f(rc[j]);
    }
    // online softmax (rows live across the 16 lanes sharing g)
    float fac[4];
#pragma unroll
    for (int j = 0; j < 4; ++j) {
      float pm = fmaxf(fmaxf(s[0][j], s[1][j]), fmaxf(s[2][j], s[3][j]));
      pm = fmaxf(pm, __shfl_xor(pm, 1));
      pm = fmaxf(pm, __shfl_xor(pm, 2));
      pm = fmaxf(pm, __shfl_xor(pm, 4));
      pm = fmaxf(pm, __shfl_xor(pm, 8));
      float mnew = fmaxf(m_run[j], pm);
      fac[j] = __expf(m_run[j] - mnew);
      m_run[j] = mnew;
    }
#pragma unroll
    for (int c = 0; c < 4; ++c)
#pragma unroll
      for (int j = 0; j < 4; ++j) s[c][j] = __expf(s[c][j] - m_run[j]);
#pragma unroll
    for (int j = 0; j < 4; ++j) {
      float rs = s[0][j] + s[1][j] + s[2][j] + s[3][j];
      rs += __shfl_xor(rs, 1);
      rs += __shfl_xor(rs, 2);
      rs += __shfl_xor(rs, 4);
      rs += __shfl_xor(rs, 8);
      l_run[j] = l_run[j] * fac[j] + rs;
    }
#pragma unroll
    for (int c = 0; c < 4; ++c)
#pragma unroll
      for (int j = 0; j < 4; ++j) acc[c][j] *= fac[j];

    // write P (bf16) to per-wave LDS region
    u16* Pw = Pl[wid];
#pragma unroll
    for (int c = 0; c < 4; ++c)
#pragma unroll
      for (int j = 0; j < 4; ++j)
        Pw[(4 * g + j) * 68 + c * 16 + i16] = f2bf(s[c][j]);
    __syncthreads();

    // O += P V
    U8 pf[2];
#pragma unroll
    for (int kk = 0; kk < 2; ++kk) {
      const u16* p = Pl[wid] + i16 * 68 + 8 * g + 32 * kk;
      pf[kk].u2[0] = *(const uint2*)p;
      pf[kk].u2[1] = *(const uint2*)(p + 4);
    }
    __builtin_amdgcn_s_setprio(1);
#pragma unroll
    for (int c = 0; c < 4; ++c) {
#pragma unroll
      for (int kk = 0; kk < 2; ++kk) {
        int row = c * 16 + i16;
        int ch = (g + 4 * kk) ^ (row & 7);
        U8 vf;
        vf.u4 = *(const uint4*)(&Vl[buf][row * 64 + ch * 8]);
        acc[c] = __builtin_amdgcn_mfma_f32_16x16x32_bf16(pf[kk].b, vf.b, acc[c], 0, 0, 0);
      }
    }
    __builtin_amdgcn_s_setprio(0);
    __syncthreads();  // protects Pl + K/V buf for next iter; drains prefetch
  }
#undef STAGE

  // epilogue: normalize, write bf16 [b][n][h*64+d]
#pragma unroll
  for (int c = 0; c < 4; ++c) {
#pragma unroll
    for (int j = 0; j < 4; ++j) {
      int n = qt * 64 + wid * 16 + 4 * g + j;
      float v = acc[c][j] / l_run[j];
      Out[((size_t)b * 512 + n) * 1024 + h * 64 + c * 16 + i16] = f2bf(v);
    }
  }
}

// ---------------- launcher ----------------
extern "C" void kernel_launch(void* const* d_in, const int* in_sizes, int n_in,
                              void* d_out, int out_size, void* d_ws, size_t ws_size,
                              hipStream_t stream) {
  const float* x = (const float*)d_in[0];
  const float* rel_bias = (const float*)d_in[1];
  const float* W_qkv = (const float*)d_in[2];
  const float* b_qkv = (const float*)d_in[3];
  const float* W_rel = (const float*)d_in[4];
  const float* b_rel = (const float*)d_in[5];
  const float* W_out = (const float*)d_in[6];
  const float* b_out = (const float*)d_in[7];
  float* out = (float*)d_out;

  char* ws = (char*)d_ws;
  u16* x_bf    = (u16*)(ws);               //  8 MB  (4096x1024); dead after qkv gemm
  u16* Vt      = (u16*)(ws);               //  8 MB  [b][h][d][n] — reuses x_bf region
  u16* wqkv_bf = (u16*)(ws + 8388608);     //  6 MB  (3072x1024)
  u16* wout_bf = (u16*)(ws + 14680064);    //  2 MB  (1024x1024)
  u16* Qw      = (u16*)(ws + 16777216);    //  8 MB  [b][h][n][d]
  u16* Kw      = (u16*)(ws + 25165824);    //  8 MB
  u16* Vw      = (u16*)(ws + 33554432);    //  8 MB
  u16* relb    = (u16*)(ws + 41943040);    // 64 MB  fragment-ordered rel
  u16* attno   = (u16*)(ws + 109051904);   //  8 MB  (4096x1024)

  k_convert_all<<<2048, 256, 0, stream>>>(x, W_qkv, W_out, x_bf, wqkv_bf, wout_bf);

  k_rel<<<dim3(8, 32, 8), 256, 0, stream>>>(rel_bias, W_rel, b_rel, relb);

  k_gemm<0><<<dim3(24, 32), 256, 0, stream>>>(x_bf, wqkv_bf, b_qkv, Qw, Kw, Vw, nullptr, 1024);

  k_vt<<<dim3(8, 128), 256, 0, stream>>>(Vw, Vt);  // overwrites x_bf (dead)

  k_attn<<<dim3(8, 16, 8), 256, 0, stream>>>(Qw, Kw, Vt, relb, attno);

  k_gemm<1><<<dim3(8, 32), 256, 0, stream>>>(attno, wout_bf, b_out, nullptr, nullptr, nullptr,
                                             out, 1024);
}

// Round 5
// 474.452 us; speedup vs baseline: 3.8139x; 3.8139x over previous
//
#include <hip/hip_runtime.h>

typedef unsigned short u16;
typedef unsigned int u32;
typedef __attribute__((ext_vector_type(8))) __bf16 bf16x8;
typedef __attribute__((ext_vector_type(4))) float f32x4;

union U8 {
  bf16x8 b;
  uint2 u2[2];
  uint4 u4;
  u16 us[8];
};

__device__ __forceinline__ u16 f2bf(float f) {
  u32 x = __float_as_uint(f);
  x += 0x7FFFu + ((x >> 16) & 1u);
  return (u16)(x >> 16);
}
__device__ __forceinline__ float bf2f(u16 u) {
  return __uint_as_float(((u32)u) << 16);
}

// async global->LDS, 16B per lane. LDS dest = wave-uniform base + lane*16.
#define GLOAD16(gp, lp)                                                          \
  __builtin_amdgcn_global_load_lds(                                              \
      (const __attribute__((address_space(1))) unsigned int*)(const void*)(gp),  \
      (__attribute__((address_space(3))) unsigned int*)(void*)(lp), 16, 0, 0)

// ---------------- f32 -> bf16 convert: x, W_qkv, W_out in one launch ----------------
__global__ void k_convert_all(const float* __restrict__ x, const float* __restrict__ wq,
                              const float* __restrict__ wo, u16* __restrict__ xb,
                              u16* __restrict__ wqb, u16* __restrict__ wob) {
  const int NX = 1048576, NQ = 786432, NO = 262144;  // float4 counts
  int idx = blockIdx.x * blockDim.x + threadIdx.x;
  int stride = gridDim.x * blockDim.x;
  for (int i = idx; i < NX + NQ + NO; i += stride) {
    const float4* s;
    ushort4* d;
    int k;
    if (i < NX) { s = (const float4*)x; d = (ushort4*)xb; k = i; }
    else if (i < NX + NQ) { s = (const float4*)wq; d = (ushort4*)wqb; k = i - NX; }
    else { s = (const float4*)wo; d = (ushort4*)wob; k = i - NX - NQ; }
    float4 v = s[k];
    ushort4 o;
    o.x = f2bf(v.x); o.y = f2bf(v.y); o.z = f2bf(v.z); o.w = f2bf(v.w);
    d[k] = o;
  }
}

// ---------------- rel projection -> MFMA-fragment-ordered bf16 ----------------
// out[tile(b,h,nt,mt)*1024 + c*256 + lane*4 + j]
//   = rel(b, h, n = nt*16 + 4*(lane>>4) + j, m = mt*64 + c*16 + (lane&15))
// tile = ((b*16+h)*32 + nt)*8 + mt.
// Wave (= fixed c) stores 64 lanes x 8B CONTIGUOUS per h (512B dense lines).
// NOTE: no min-waves launch bound (R4's (256,3) capped VGPR at 84 -> spill ->
// 6 GB scratch traffic). unroll 1 on j keeps live set ~one j iteration.
__global__ __launch_bounds__(256) void k_rel(const float* __restrict__ rb,
                                             const float* __restrict__ Wr,
                                             const float* __restrict__ br,
                                             u16* __restrict__ out) {
  __shared__ float Wl[16][32];
  __shared__ float bl[16];
  int t = threadIdx.x;
  ((float*)Wl)[t] = Wr[t];
  ((float*)Wl)[t + 256] = Wr[t + 256];
  if (t < 16) bl[t] = br[t];
  __syncthreads();

  const int c = t >> 6, lane = t & 63, g = lane >> 4, i16 = lane & 15;
  const int mt = blockIdx.x, nt = blockIdx.y, b = blockIdx.z;

  u32 pk[16][2];
#pragma unroll
  for (int h = 0; h < 16; ++h) pk[h][0] = pk[h][1] = 0u;

#pragma unroll 1
  for (int j = 0; j < 4; ++j) {
    size_t prow = ((size_t)(b * 512 + nt * 16 + 4 * g + j)) * 512 + mt * 64 + c * 16 + i16;
    const float4* rp = (const float4*)(rb + prow * 32);
    float4 r4[8];
#pragma unroll
    for (int q = 0; q < 8; ++q) r4[q] = rp[q];
#pragma unroll
    for (int h = 0; h < 16; ++h) {
      float acc = bl[h];
      const float* w = Wl[h];
#pragma unroll
      for (int q = 0; q < 8; ++q) {
        acc += r4[q].x * w[4 * q + 0] + r4[q].y * w[4 * q + 1] +
               r4[q].z * w[4 * q + 2] + r4[q].w * w[4 * q + 3];
      }
      pk[h][j >> 1] |= (u32)f2bf(acc) << (16 * (j & 1));
    }
  }

#pragma unroll
  for (int h = 0; h < 16; ++h) {
    uint2 w;
    w.x = pk[h][0];
    w.y = pk[h][1];
    size_t o = (((size_t)(b * 16 + h) * 32 + nt) * 8 + mt) * 1024 + c * 256 + lane * 4;
    *(uint2*)(out + o) = w;
  }
}

// ---------------- GEMM: C(M x N) = A(M x K) * W(N x K)^T + bias ----------------
// m97-style: 128x128 tile, BK=64, global_load_lds(16B) staging into linear LDS,
// both-sides XOR swizzle (global source chunk ^= r&7; ds_read chunk ^= row&7).
// MODE 0: qkv -> scatter bf16 into Q,K,V [b][h][n][d]
// MODE 1: out -> f32 C row-major with bias
template <int MODE>
__global__ __launch_bounds__(256) void k_gemm(const u16* __restrict__ A,
                                              const u16* __restrict__ Bm,
                                              const float* __restrict__ bias,
                                              u16* __restrict__ Qo, u16* __restrict__ Ko,
                                              u16* __restrict__ Vo, float* __restrict__ Co,
                                              int K) {
  __shared__ u16 Al[128 * 64];
  __shared__ u16 Bl[128 * 64];
  const int t = threadIdx.x;
  const int lane = t & 63, wid = t >> 6;
  const int g = lane >> 4, i16 = lane & 15;
  const int wm = wid >> 1, wn = wid & 1;
  const int bm = blockIdx.y, bn = blockIdx.x;

  f32x4 zero = {0.f, 0.f, 0.f, 0.f};
  f32x4 acc[4][4];
#pragma unroll
  for (int mi = 0; mi < 4; ++mi)
#pragma unroll
    for (int ni = 0; ni < 4; ++ni) acc[mi][ni] = zero;

  int srow[4], sgc[4];
#pragma unroll
  for (int i = 0; i < 4; ++i) {
    int ch = wid * 256 + i * 64 + lane;
    int r = ch >> 3, cs = ch & 7;
    srow[i] = r;
    sgc[i] = cs ^ (r & 7);
  }

  for (int k0 = 0; k0 < K; k0 += 64) {
    __syncthreads();
#pragma unroll
    for (int i = 0; i < 4; ++i) {
      const u16* ga = A + (size_t)(bm * 128 + srow[i]) * K + k0 + sgc[i] * 8;
      const u16* gb = Bm + (size_t)(bn * 128 + srow[i]) * K + k0 + sgc[i] * 8;
      GLOAD16(ga, Al + (size_t)(wid * 256 + i * 64) * 8);
      GLOAD16(gb, Bl + (size_t)(wid * 256 + i * 64) * 8);
    }
    __syncthreads();

#pragma unroll
    for (int kk = 0; kk < 2; ++kk) {
      U8 af[4], bfr[4];
#pragma unroll
      for (int mi = 0; mi < 4; ++mi) {
        int row = wm * 64 + mi * 16 + i16;
        int ch = (g + 4 * kk) ^ (row & 7);
        af[mi].u4 = *(const uint4*)(Al + row * 64 + ch * 8);
      }
#pragma unroll
      for (int ni = 0; ni < 4; ++ni) {
        int row = wn * 64 + ni * 16 + i16;
        int ch = (g + 4 * kk) ^ (row & 7);
        bfr[ni].u4 = *(const uint4*)(Bl + row * 64 + ch * 8);
      }
#pragma unroll
      for (int mi = 0; mi < 4; ++mi)
#pragma unroll
        for (int ni = 0; ni < 4; ++ni)
          acc[mi][ni] = __builtin_amdgcn_mfma_f32_16x16x32_bf16(af[mi].b, bfr[ni].b,
                                                                acc[mi][ni], 0, 0, 0);
    }
  }

#pragma unroll
  for (int mi = 0; mi < 4; ++mi) {
#pragma unroll
    for (int ni = 0; ni < 4; ++ni) {
      int colb = bn * 128 + wn * 64 + ni * 16;
      int col = colb + i16;
#pragma unroll
      for (int j = 0; j < 4; ++j) {
        int row = bm * 128 + wm * 64 + mi * 16 + 4 * g + j;
        float v = acc[mi][ni][j] + bias[col];
        if (MODE == 0) {
          int tt = col >> 10;
          int h = (col >> 6) & 15;
          int d = col & 63;
          int b = row >> 9;
          int n = row & 511;
          u16* dst = (tt == 0) ? Qo : ((tt == 1) ? Ko : Vo);
          dst[((size_t)(b * 16 + h) * 512 + n) * 64 + d] = f2bf(v);
        } else {
          Co[(size_t)row * 1024 + col] = v;
        }
      }
    }
  }
}

// ---------------- V transpose: [bh][n][d] -> [bh][d][n] ----------------
__global__ __launch_bounds__(256) void k_vt(const u16* __restrict__ V, u16* __restrict__ Vt) {
  __shared__ u16 Tl[64][72];
  const int t = threadIdx.x;
  const int n0 = blockIdx.x * 64;
  const size_t bh = blockIdx.y;
#pragma unroll
  for (int i = 0; i < 2; ++i) {
    int c = i * 256 + t;
    int r = c >> 3, c8 = (c & 7) * 8;
    U8 v;
    v.u4 = *(const uint4*)(V + (bh * 512 + n0 + r) * 64 + c8);
    *(uint2*)&Tl[r][c8] = v.u2[0];
    *(uint2*)&Tl[r][c8 + 4] = v.u2[1];
  }
  __syncthreads();
#pragma unroll
  for (int i = 0; i < 2; ++i) {
    int c = i * 256 + t;
    int d = c >> 3, n8 = (c & 7) * 8;
    U8 o;
#pragma unroll
    for (int j = 0; j < 8; ++j) o.us[j] = Tl[n8 + j][d];
    *(uint4*)(Vt + (bh * 64 + d) * 512 + n0 + n8) = o.u4;
  }
}

// ---------------- fused attention: softmax(Q K^T * scale + rel) V ----------------
// grid (qt=8, h=16, b=8), 256 threads = 4 waves, each wave owns 16 q-rows.
// K/Vt double-buffered via global_load_lds, prefetch issued before compute.
// rel read as 4x uint2 per thread per tile (dense fragment-ordered layout).
__global__ __launch_bounds__(256) void k_attn(const u16* __restrict__ Q,
                                              const u16* __restrict__ Kb,
                                              const u16* __restrict__ Vtb,
                                              const u16* __restrict__ Rel,
                                              u16* __restrict__ Out) {
  __shared__ u16 Kl[2][64 * 64];
  __shared__ u16 Vl[2][64 * 64];
  __shared__ u16 Pl[4][16 * 68];

  const int qt = blockIdx.x, h = blockIdx.y, b = blockIdx.z;
  const int t = threadIdx.x, lane = t & 63, wid = t >> 6;
  const int g = lane >> 4, i16 = lane & 15;
  const size_t bh = (size_t)(b * 16 + h);

  // Q fragments (held in registers for entire kernel)
  const u16* Qg = Q + (bh * 512 + qt * 64 + wid * 16 + i16) * 64;
  U8 qf[2];
  qf[0].u4 = *(const uint4*)(Qg + 8 * g);
  qf[1].u4 = *(const uint4*)(Qg + 8 * g + 32);

  float m_run[4], l_run[4];
  f32x4 zero = {0.f, 0.f, 0.f, 0.f};
  f32x4 acc[4];
#pragma unroll
  for (int c = 0; c < 4; ++c) acc[c] = zero;
#pragma unroll
  for (int j = 0; j < 4; ++j) { m_run[j] = -1e30f; l_run[j] = 0.f; }

  int srow[2], sgc[2];
#pragma unroll
  for (int i = 0; i < 2; ++i) {
    int ch = wid * 128 + i * 64 + lane;
    int r = ch >> 3, cs = ch & 7;
    srow[i] = r;
    sgc[i] = cs ^ (r & 7);
  }

  const u16* Kg0 = Kb + bh * 512 * 64;
  const u16* Vg0 = Vtb + bh * 64 * 512;
  // fragment-ordered rel: tile(b,h, nt=qt*4+wid, mt=it)*1024 + c*256 + lane*4 + j
  const u16* Rg = Rel + ((bh * 32 + qt * 4 + wid) * 8) * 1024 + lane * 4;

#define STAGE(buf, m0)                                                                  \
  do {                                                                                  \
    _Pragma("unroll") for (int i = 0; i < 2; ++i) {                                     \
      GLOAD16(Kg0 + (size_t)((m0) + srow[i]) * 64 + sgc[i] * 8,                         \
              &Kl[buf][(size_t)(wid * 128 + i * 64) * 8]);                              \
      GLOAD16(Vg0 + (size_t)srow[i] * 512 + (m0) + sgc[i] * 8,                          \
              &Vl[buf][(size_t)(wid * 128 + i * 64) * 8]);                              \
    }                                                                                   \
  } while (0)

  STAGE(0, 0);
  __syncthreads();

  for (int it = 0; it < 8; ++it) {
    const int buf = it & 1;
    if (it < 7) STAGE(buf ^ 1, it * 64 + 64);

    // rel fragments: 4 x uint2 (dense per wave), in flight under QK^T
    uint2 rl[4];
#pragma unroll
    for (int c = 0; c < 4; ++c) rl[c] = *(const uint2*)(Rg + it * 1024 + c * 256);

    // S = Q K^T  (per wave: 16 x 64)
    f32x4 s[4];
#pragma unroll
    for (int c = 0; c < 4; ++c) s[c] = zero;
    __builtin_amdgcn_s_setprio(1);
#pragma unroll
    for (int c = 0; c < 4; ++c) {
#pragma unroll
      for (int kk = 0; kk < 2; ++kk) {
        int row = c * 16 + i16;
        int ch = (g + 4 * kk) ^ (row & 7);
        U8 kf;
        kf.u4 = *(const uint4*)(&Kl[buf][row * 64 + ch * 8]);
        s[c] = __builtin_amdgcn_mfma_f32_16x16x32_bf16(qf[kk].b, kf.b, s[c], 0, 0, 0);
      }
    }
    __builtin_amdgcn_s_setprio(0);

    // scale + rel bias
#pragma unroll
    for (int c = 0; c < 4; ++c) {
      const u16* rc = (const u16*)&rl[c];
#pragma unroll
      for (int j = 0; j < 4; ++j) s[c][j] = s[c][j] * 0.125f + bf2f(rc[j]);
    }
    // online softmax (rows live across the 16 lanes sharing g)
    float fac[4];
#pragma unroll
    for (int j = 0; j < 4; ++j) {
      float pm = fmaxf(fmaxf(s[0][j], s[1][j]), fmaxf(s[2][j], s[3][j]));
      pm = fmaxf(pm, __shfl_xor(pm, 1));
      pm = fmaxf(pm, __shfl_xor(pm, 2));
      pm = fmaxf(pm, __shfl_xor(pm, 4));
      pm = fmaxf(pm, __shfl_xor(pm, 8));
      float mnew = fmaxf(m_run[j], pm);
      fac[j] = __expf(m_run[j] - mnew);
      m_run[j] = mnew;
    }
#pragma unroll
    for (int c = 0; c < 4; ++c)
#pragma unroll
      for (int j = 0; j < 4; ++j) s[c][j] = __expf(s[c][j] - m_run[j]);
#pragma unroll
    for (int j = 0; j < 4; ++j) {
      float rs = s[0][j] + s[1][j] + s[2][j] + s[3][j];
      rs += __shfl_xor(rs, 1);
      rs += __shfl_xor(rs, 2);
      rs += __shfl_xor(rs, 4);
      rs += __shfl_xor(rs, 8);
      l_run[j] = l_run[j] * fac[j] + rs;
    }
#pragma unroll
    for (int c = 0; c < 4; ++c)
#pragma unroll
      for (int j = 0; j < 4; ++j) acc[c][j] *= fac[j];

    // write P (bf16) to per-wave LDS region
    u16* Pw = Pl[wid];
#pragma unroll
    for (int c = 0; c < 4; ++c)
#pragma unroll
      for (int j = 0; j < 4; ++j)
        Pw[(4 * g + j) * 68 + c * 16 + i16] = f2bf(s[c][j]);
    __syncthreads();

    // O += P V
    U8 pf[2];
#pragma unroll
    for (int kk = 0; kk < 2; ++kk) {
      const u16* p = Pl[wid] + i16 * 68 + 8 * g + 32 * kk;
      pf[kk].u2[0] = *(const uint2*)p;
      pf[kk].u2[1] = *(const uint2*)(p + 4);
    }
    __builtin_amdgcn_s_setprio(1);
#pragma unroll
    for (int c = 0; c < 4; ++c) {
#pragma unroll
      for (int kk = 0; kk < 2; ++kk) {
        int row = c * 16 + i16;
        int ch = (g + 4 * kk) ^ (row & 7);
        U8 vf;
        vf.u4 = *(const uint4*)(&Vl[buf][row * 64 + ch * 8]);
        acc[c] = __builtin_amdgcn_mfma_f32_16x16x32_bf16(pf[kk].b, vf.b, acc[c], 0, 0, 0);
      }
    }
    __builtin_amdgcn_s_setprio(0);
    __syncthreads();  // protects Pl + K/V buf for next iter; drains prefetch
  }
#undef STAGE

  // epilogue: normalize, write bf16 [b][n][h*64+d]
#pragma unroll
  for (int c = 0; c < 4; ++c) {
#pragma unroll
    for (int j = 0; j < 4; ++j) {
      int n = qt * 64 + wid * 16 + 4 * g + j;
      float v = acc[c][j] / l_run[j];
      Out[((size_t)b * 512 + n) * 1024 + h * 64 + c * 16 + i16] = f2bf(v);
    }
  }
}

// ---------------- launcher ----------------
extern "C" void kernel_launch(void* const* d_in, const int* in_sizes, int n_in,
                              void* d_out, int out_size, void* d_ws, size_t ws_size,
                              hipStream_t stream) {
  const float* x = (const float*)d_in[0];
  const float* rel_bias = (const float*)d_in[1];
  const float* W_qkv = (const float*)d_in[2];
  const float* b_qkv = (const float*)d_in[3];
  const float* W_rel = (const float*)d_in[4];
  const float* b_rel = (const float*)d_in[5];
  const float* W_out = (const float*)d_in[6];
  const float* b_out = (const float*)d_in[7];
  float* out = (float*)d_out;

  char* ws = (char*)d_ws;
  u16* x_bf    = (u16*)(ws);               //  8 MB  (4096x1024); dead after qkv gemm
  u16* Vt      = (u16*)(ws);               //  8 MB  [b][h][d][n] — reuses x_bf region
  u16* wqkv_bf = (u16*)(ws + 8388608);     //  6 MB  (3072x1024)
  u16* wout_bf = (u16*)(ws + 14680064);    //  2 MB  (1024x1024)
  u16* Qw      = (u16*)(ws + 16777216);    //  8 MB  [b][h][n][d]
  u16* Kw      = (u16*)(ws + 25165824);    //  8 MB
  u16* Vw      = (u16*)(ws + 33554432);    //  8 MB
  u16* relb    = (u16*)(ws + 41943040);    // 64 MB  fragment-ordered rel
  u16* attno   = (u16*)(ws + 109051904);   //  8 MB  (4096x1024)

  k_convert_all<<<2048, 256, 0, stream>>>(x, W_qkv, W_out, x_bf, wqkv_bf, wout_bf);

  k_rel<<<dim3(8, 32, 8), 256, 0, stream>>>(rel_bias, W_rel, b_rel, relb);

  k_gemm<0><<<dim3(24, 32), 256, 0, stream>>>(x_bf, wqkv_bf, b_qkv, Qw, Kw, Vw, nullptr, 1024);

  k_vt<<<dim3(8, 128), 256, 0, stream>>>(Vw, Vt);  // overwrites x_bf (dead)

  k_attn<<<dim3(8, 16, 8), 256, 0, stream>>>(Qw, Kw, Vt, relb, attno);

  k_gemm<1><<<dim3(8, 32), 256, 0, stream>>>(attno, wout_bf, b_out, nullptr, nullptr, nullptr,
                                             out, 1024);
}

// Round 6
// 202.439 us; speedup vs baseline: 8.9385x; 2.3437x over previous
//
#include <hip/hip_runtime.h>

typedef unsigned short u16;
typedef unsigned int u32;
typedef __attribute__((ext_vector_type(8))) __bf16 bf16x8;
typedef __attribute__((ext_vector_type(4))) float f32x4;

union U8 {
  bf16x8 b;
  uint2 u2[2];
  uint4 u4;
  u16 us[8];
};

__device__ __forceinline__ u16 f2bf(float f) {
  u32 x = __float_as_uint(f);
  x += 0x7FFFu + ((x >> 16) & 1u);
  return (u16)(x >> 16);
}
__device__ __forceinline__ float bf2f(u16 u) {
  return __uint_as_float(((u32)u) << 16);
}

// async global->LDS, 16B per lane. LDS dest = wave-uniform base + lane*16.
#define GLOAD16(gp, lp)                                                          \
  __builtin_amdgcn_global_load_lds(                                              \
      (const __attribute__((address_space(1))) unsigned int*)(const void*)(gp),  \
      (__attribute__((address_space(3))) unsigned int*)(void*)(lp), 16, 0, 0)

// ---------------- f32 -> bf16 convert: x, W_qkv, W_out in one launch ----------------
__global__ void k_convert_all(const float* __restrict__ x, const float* __restrict__ wq,
                              const float* __restrict__ wo, u16* __restrict__ xb,
                              u16* __restrict__ wqb, u16* __restrict__ wob) {
  const int NX = 1048576, NQ = 786432, NO = 262144;  // float4 counts
  int idx = blockIdx.x * blockDim.x + threadIdx.x;
  int stride = gridDim.x * blockDim.x;
  for (int i = idx; i < NX + NQ + NO; i += stride) {
    const float4* s;
    ushort4* d;
    int k;
    if (i < NX) { s = (const float4*)x; d = (ushort4*)xb; k = i; }
    else if (i < NX + NQ) { s = (const float4*)wq; d = (ushort4*)wqb; k = i - NX; }
    else { s = (const float4*)wo; d = (ushort4*)wob; k = i - NX - NQ; }
    float4 v = s[k];
    ushort4 o;
    o.x = f2bf(v.x); o.y = f2bf(v.y); o.z = f2bf(v.z); o.w = f2bf(v.w);
    d[k] = o;
  }
}

// ---------------- rel projection -> MFMA-fragment-ordered bf16 ----------------
// Fragment layout (consumed by k_attn):
//   out[tile(b,h,nt,mt)*1024 + c*256 + lane*4 + j]
//     = rel(b, h, n = nt*16 + 4*(lane>>4) + j, m = mt*64 + c*16 + (lane&15))
//   tile = ((b*16+h)*32 + nt)*8 + mt.
// ONE (n,m) POINT PER THREAD (R5's 4-points/thread ran VGPR=256 + spill):
//   grid (mt=8, ntg=nt*4+g=128, b=8); t = i16 + 16*j + 64*c.
//   Live set: 8 float4 inputs (32) + 16 accumulators (16) -> no spill.
//   Per wave per h the 2B stores cover one dense 128B segment (i16*4+j perm).
__global__ __launch_bounds__(256) void k_rel(const float* __restrict__ rb,
                                             const float* __restrict__ Wr,
                                             const float* __restrict__ br,
                                             u16* __restrict__ out) {
  __shared__ float Wl[16][32];
  __shared__ float bl[16];
  int t = threadIdx.x;
  ((float*)Wl)[t] = Wr[t];
  ((float*)Wl)[t + 256] = Wr[t + 256];
  if (t < 16) bl[t] = br[t];
  __syncthreads();

  const int i16 = t & 15, j = (t >> 4) & 3, c = t >> 6;
  const int mt = blockIdx.x, ntg = blockIdx.y, b = blockIdx.z;
  const int nt = ntg >> 2, g = ntg & 3;
  const int n = nt * 16 + 4 * g + j;
  const int m = mt * 64 + c * 16 + i16;

  const float4* rp = (const float4*)(rb + ((size_t)(b * 512 + n) * 512 + m) * 32);
  float4 r4[8];
#pragma unroll
  for (int q = 0; q < 8; ++q) r4[q] = rp[q];

  const size_t obase =
      (((size_t)(b * 16) * 32 + nt) * 8 + mt) * 1024 + c * 256 + (g * 16 + i16) * 4 + j;
#pragma unroll
  for (int h = 0; h < 16; ++h) {
    float acc = bl[h];
    const float* w = Wl[h];
#pragma unroll
    for (int q = 0; q < 8; ++q) {
      acc += r4[q].x * w[4 * q + 0] + r4[q].y * w[4 * q + 1] +
             r4[q].z * w[4 * q + 2] + r4[q].w * w[4 * q + 3];
    }
    out[obase + (size_t)h * 262144] = f2bf(acc);
  }
}

// ---------------- GEMM: C(M x N) = A(M x K) * W(N x K)^T + bias ----------------
// m97-style: 128x128 tile, BK=64, global_load_lds(16B) staging into linear LDS,
// both-sides XOR swizzle (global source chunk ^= r&7; ds_read chunk ^= row&7).
// MODE 0: qkv -> scatter bf16 into Q,K,V [b][h][n][d]
// MODE 1: out -> f32 C row-major with bias
template <int MODE>
__global__ __launch_bounds__(256) void k_gemm(const u16* __restrict__ A,
                                              const u16* __restrict__ Bm,
                                              const float* __restrict__ bias,
                                              u16* __restrict__ Qo, u16* __restrict__ Ko,
                                              u16* __restrict__ Vo, float* __restrict__ Co,
                                              int K) {
  __shared__ u16 Al[128 * 64];
  __shared__ u16 Bl[128 * 64];
  const int t = threadIdx.x;
  const int lane = t & 63, wid = t >> 6;
  const int g = lane >> 4, i16 = lane & 15;
  const int wm = wid >> 1, wn = wid & 1;
  const int bm = blockIdx.y, bn = blockIdx.x;

  f32x4 zero = {0.f, 0.f, 0.f, 0.f};
  f32x4 acc[4][4];
#pragma unroll
  for (int mi = 0; mi < 4; ++mi)
#pragma unroll
    for (int ni = 0; ni < 4; ++ni) acc[mi][ni] = zero;

  int srow[4], sgc[4];
#pragma unroll
  for (int i = 0; i < 4; ++i) {
    int ch = wid * 256 + i * 64 + lane;
    int r = ch >> 3, cs = ch & 7;
    srow[i] = r;
    sgc[i] = cs ^ (r & 7);
  }

  for (int k0 = 0; k0 < K; k0 += 64) {
    __syncthreads();
#pragma unroll
    for (int i = 0; i < 4; ++i) {
      const u16* ga = A + (size_t)(bm * 128 + srow[i]) * K + k0 + sgc[i] * 8;
      const u16* gb = Bm + (size_t)(bn * 128 + srow[i]) * K + k0 + sgc[i] * 8;
      GLOAD16(ga, Al + (size_t)(wid * 256 + i * 64) * 8);
      GLOAD16(gb, Bl + (size_t)(wid * 256 + i * 64) * 8);
    }
    __syncthreads();

#pragma unroll
    for (int kk = 0; kk < 2; ++kk) {
      U8 af[4], bfr[4];
#pragma unroll
      for (int mi = 0; mi < 4; ++mi) {
        int row = wm * 64 + mi * 16 + i16;
        int ch = (g + 4 * kk) ^ (row & 7);
        af[mi].u4 = *(const uint4*)(Al + row * 64 + ch * 8);
      }
#pragma unroll
      for (int ni = 0; ni < 4; ++ni) {
        int row = wn * 64 + ni * 16 + i16;
        int ch = (g + 4 * kk) ^ (row & 7);
        bfr[ni].u4 = *(const uint4*)(Bl + row * 64 + ch * 8);
      }
#pragma unroll
      for (int mi = 0; mi < 4; ++mi)
#pragma unroll
        for (int ni = 0; ni < 4; ++ni)
          acc[mi][ni] = __builtin_amdgcn_mfma_f32_16x16x32_bf16(af[mi].b, bfr[ni].b,
                                                                acc[mi][ni], 0, 0, 0);
    }
  }

#pragma unroll
  for (int mi = 0; mi < 4; ++mi) {
#pragma unroll
    for (int ni = 0; ni < 4; ++ni) {
      int colb = bn * 128 + wn * 64 + ni * 16;
      int col = colb + i16;
#pragma unroll
      for (int j = 0; j < 4; ++j) {
        int row = bm * 128 + wm * 64 + mi * 16 + 4 * g + j;
        float v = acc[mi][ni][j] + bias[col];
        if (MODE == 0) {
          int tt = col >> 10;
          int h = (col >> 6) & 15;
          int d = col & 63;
          int b = row >> 9;
          int n = row & 511;
          u16* dst = (tt == 0) ? Qo : ((tt == 1) ? Ko : Vo);
          dst[((size_t)(b * 16 + h) * 512 + n) * 64 + d] = f2bf(v);
        } else {
          Co[(size_t)row * 1024 + col] = v;
        }
      }
    }
  }
}

// ---------------- V transpose: [bh][n][d] -> [bh][d][n] ----------------
__global__ __launch_bounds__(256) void k_vt(const u16* __restrict__ V, u16* __restrict__ Vt) {
  __shared__ u16 Tl[64][72];
  const int t = threadIdx.x;
  const int n0 = blockIdx.x * 64;
  const size_t bh = blockIdx.y;
#pragma unroll
  for (int i = 0; i < 2; ++i) {
    int c = i * 256 + t;
    int r = c >> 3, c8 = (c & 7) * 8;
    U8 v;
    v.u4 = *(const uint4*)(V + (bh * 512 + n0 + r) * 64 + c8);
    *(uint2*)&Tl[r][c8] = v.u2[0];
    *(uint2*)&Tl[r][c8 + 4] = v.u2[1];
  }
  __syncthreads();
#pragma unroll
  for (int i = 0; i < 2; ++i) {
    int c = i * 256 + t;
    int d = c >> 3, n8 = (c & 7) * 8;
    U8 o;
#pragma unroll
    for (int j = 0; j < 8; ++j) o.us[j] = Tl[n8 + j][d];
    *(uint4*)(Vt + (bh * 64 + d) * 512 + n0 + n8) = o.u4;
  }
}

// ---------------- fused attention: softmax(Q K^T * scale + rel) V ----------------
// grid (qt=8, h=16, b=8), 256 threads = 4 waves, each wave owns 16 q-rows.
// K/Vt double-buffered via global_load_lds, prefetch issued before compute.
// rel read as 4x uint2 per thread per tile (dense fragment-ordered layout).
__global__ __launch_bounds__(256) void k_attn(const u16* __restrict__ Q,
                                              const u16* __restrict__ Kb,
                                              const u16* __restrict__ Vtb,
                                              const u16* __restrict__ Rel,
                                              u16* __restrict__ Out) {
  __shared__ u16 Kl[2][64 * 64];
  __shared__ u16 Vl[2][64 * 64];
  __shared__ u16 Pl[4][16 * 68];

  const int qt = blockIdx.x, h = blockIdx.y, b = blockIdx.z;
  const int t = threadIdx.x, lane = t & 63, wid = t >> 6;
  const int g = lane >> 4, i16 = lane & 15;
  const size_t bh = (size_t)(b * 16 + h);

  // Q fragments (held in registers for entire kernel)
  const u16* Qg = Q + (bh * 512 + qt * 64 + wid * 16 + i16) * 64;
  U8 qf[2];
  qf[0].u4 = *(const uint4*)(Qg + 8 * g);
  qf[1].u4 = *(const uint4*)(Qg + 8 * g + 32);

  float m_run[4], l_run[4];
  f32x4 zero = {0.f, 0.f, 0.f, 0.f};
  f32x4 acc[4];
#pragma unroll
  for (int c = 0; c < 4; ++c) acc[c] = zero;
#pragma unroll
  for (int j = 0; j < 4; ++j) { m_run[j] = -1e30f; l_run[j] = 0.f; }

  int srow[2], sgc[2];
#pragma unroll
  for (int i = 0; i < 2; ++i) {
    int ch = wid * 128 + i * 64 + lane;
    int r = ch >> 3, cs = ch & 7;
    srow[i] = r;
    sgc[i] = cs ^ (r & 7);
  }

  const u16* Kg0 = Kb + bh * 512 * 64;
  const u16* Vg0 = Vtb + bh * 64 * 512;
  // fragment-ordered rel: tile(b,h, nt=qt*4+wid, mt=it)*1024 + c*256 + lane*4 + j
  const u16* Rg = Rel + ((bh * 32 + qt * 4 + wid) * 8) * 1024 + lane * 4;

#define STAGE(buf, m0)                                                                  \
  do {                                                                                  \
    _Pragma("unroll") for (int i = 0; i < 2; ++i) {                                     \
      GLOAD16(Kg0 + (size_t)((m0) + srow[i]) * 64 + sgc[i] * 8,                         \
              &Kl[buf][(size_t)(wid * 128 + i * 64) * 8]);                              \
      GLOAD16(Vg0 + (size_t)srow[i] * 512 + (m0) + sgc[i] * 8,                          \
              &Vl[buf][(size_t)(wid * 128 + i * 64) * 8]);                              \
    }                                                                                   \
  } while (0)

  STAGE(0, 0);
  __syncthreads();

  for (int it = 0; it < 8; ++it) {
    const int buf = it & 1;
    if (it < 7) STAGE(buf ^ 1, it * 64 + 64);

    // rel fragments: 4 x uint2 (dense per wave), in flight under QK^T
    uint2 rl[4];
#pragma unroll
    for (int c = 0; c < 4; ++c) rl[c] = *(const uint2*)(Rg + it * 1024 + c * 256);

    // S = Q K^T  (per wave: 16 x 64)
    f32x4 s[4];
#pragma unroll
    for (int c = 0; c < 4; ++c) s[c] = zero;
    __builtin_amdgcn_s_setprio(1);
#pragma unroll
    for (int c = 0; c < 4; ++c) {
#pragma unroll
      for (int kk = 0; kk < 2; ++kk) {
        int row = c * 16 + i16;
        int ch = (g + 4 * kk) ^ (row & 7);
        U8 kf;
        kf.u4 = *(const uint4*)(&Kl[buf][row * 64 + ch * 8]);
        s[c] = __builtin_amdgcn_mfma_f32_16x16x32_bf16(qf[kk].b, kf.b, s[c], 0, 0, 0);
      }
    }
    __builtin_amdgcn_s_setprio(0);

    // scale + rel bias
#pragma unroll
    for (int c = 0; c < 4; ++c) {
      const u16* rc = (const u16*)&rl[c];
#pragma unroll
      for (int j = 0; j < 4; ++j) s[c][j] = s[c][j] * 0.125f + bf2f(rc[j]);
    }
    // online softmax (rows live across the 16 lanes sharing g)
    float fac[4];
#pragma unroll
    for (int j = 0; j < 4; ++j) {
      float pm = fmaxf(fmaxf(s[0][j], s[1][j]), fmaxf(s[2][j], s[3][j]));
      pm = fmaxf(pm, __shfl_xor(pm, 1));
      pm = fmaxf(pm, __shfl_xor(pm, 2));
      pm = fmaxf(pm, __shfl_xor(pm, 4));
      pm = fmaxf(pm, __shfl_xor(pm, 8));
      float mnew = fmaxf(m_run[j], pm);
      fac[j] = __expf(m_run[j] - mnew);
      m_run[j] = mnew;
    }
#pragma unroll
    for (int c = 0; c < 4; ++c)
#pragma unroll
      for (int j = 0; j < 4; ++j) s[c][j] = __expf(s[c][j] - m_run[j]);
#pragma unroll
    for (int j = 0; j < 4; ++j) {
      float rs = s[0][j] + s[1][j] + s[2][j] + s[3][j];
      rs += __shfl_xor(rs, 1);
      rs += __shfl_xor(rs, 2);
      rs += __shfl_xor(rs, 4);
      rs += __shfl_xor(rs, 8);
      l_run[j] = l_run[j] * fac[j] + rs;
    }
#pragma unroll
    for (int c = 0; c < 4; ++c)
#pragma unroll
      for (int j = 0; j < 4; ++j) acc[c][j] *= fac[j];

    // write P (bf16) to per-wave LDS region
    u16* Pw = Pl[wid];
#pragma unroll
    for (int c = 0; c < 4; ++c)
#pragma unroll
      for (int j = 0; j < 4; ++j)
        Pw[(4 * g + j) * 68 + c * 16 + i16] = f2bf(s[c][j]);
    __syncthreads();

    // O += P V
    U8 pf[2];
#pragma unroll
    for (int kk = 0; kk < 2; ++kk) {
      const u16* p = Pl[wid] + i16 * 68 + 8 * g + 32 * kk;
      pf[kk].u2[0] = *(const uint2*)p;
      pf[kk].u2[1] = *(const uint2*)(p + 4);
    }
    __builtin_amdgcn_s_setprio(1);
#pragma unroll
    for (int c = 0; c < 4; ++c) {
#pragma unroll
      for (int kk = 0; kk < 2; ++kk) {
        int row = c * 16 + i16;
        int ch = (g + 4 * kk) ^ (row & 7);
        U8 vf;
        vf.u4 = *(const uint4*)(&Vl[buf][row * 64 + ch * 8]);
        acc[c] = __builtin_amdgcn_mfma_f32_16x16x32_bf16(pf[kk].b, vf.b, acc[c], 0, 0, 0);
      }
    }
    __builtin_amdgcn_s_setprio(0);
    __syncthreads();  // protects Pl + K/V buf for next iter; drains prefetch
  }
#undef STAGE

  // epilogue: normalize, write bf16 [b][n][h*64+d]
#pragma unroll
  for (int c = 0; c < 4; ++c) {
#pragma unroll
    for (int j = 0; j < 4; ++j) {
      int n = qt * 64 + wid * 16 + 4 * g + j;
      float v = acc[c][j] / l_run[j];
      Out[((size_t)b * 512 + n) * 1024 + h * 64 + c * 16 + i16] = f2bf(v);
    }
  }
}

// ---------------- launcher ----------------
extern "C" void kernel_launch(void* const* d_in, const int* in_sizes, int n_in,
                              void* d_out, int out_size, void* d_ws, size_t ws_size,
                              hipStream_t stream) {
  const float* x = (const float*)d_in[0];
  const float* rel_bias = (const float*)d_in[1];
  const float* W_qkv = (const float*)d_in[2];
  const float* b_qkv = (const float*)d_in[3];
  const float* W_rel = (const float*)d_in[4];
  const float* b_rel = (const float*)d_in[5];
  const float* W_out = (const float*)d_in[6];
  const float* b_out = (const float*)d_in[7];
  float* out = (float*)d_out;

  char* ws = (char*)d_ws;
  u16* x_bf    = (u16*)(ws);               //  8 MB  (4096x1024); dead after qkv gemm
  u16* Vt      = (u16*)(ws);               //  8 MB  [b][h][d][n] — reuses x_bf region
  u16* wqkv_bf = (u16*)(ws + 8388608);     //  6 MB  (3072x1024)
  u16* wout_bf = (u16*)(ws + 14680064);    //  2 MB  (1024x1024)
  u16* Qw      = (u16*)(ws + 16777216);    //  8 MB  [b][h][n][d]
  u16* Kw      = (u16*)(ws + 25165824);    //  8 MB
  u16* Vw      = (u16*)(ws + 33554432);    //  8 MB
  u16* relb    = (u16*)(ws + 41943040);    // 64 MB  fragment-ordered rel
  u16* attno   = (u16*)(ws + 109051904);   //  8 MB  (4096x1024)

  k_convert_all<<<2048, 256, 0, stream>>>(x, W_qkv, W_out, x_bf, wqkv_bf, wout_bf);

  k_rel<<<dim3(8, 128, 8), 256, 0, stream>>>(rel_bias, W_rel, b_rel, relb);

  k_gemm<0><<<dim3(24, 32), 256, 0, stream>>>(x_bf, wqkv_bf, b_qkv, Qw, Kw, Vw, nullptr, 1024);

  k_vt<<<dim3(8, 128), 256, 0, stream>>>(Vw, Vt);  // overwrites x_bf (dead)

  k_attn<<<dim3(8, 16, 8), 256, 0, stream>>>(Qw, Kw, Vt, relb, attno);

  k_gemm<1><<<dim3(8, 32), 256, 0, stream>>>(attno, wout_bf, b_out, nullptr, nullptr, nullptr,
                                             out, 1024);
}

// Round 7
// 186.755 us; speedup vs baseline: 9.6892x; 1.0840x over previous
//
#include <hip/hip_runtime.h>

typedef unsigned short u16;
typedef unsigned int u32;
typedef __attribute__((ext_vector_type(8))) __bf16 bf16x8;
typedef __attribute__((ext_vector_type(4))) float f32x4;

union U8 {
  bf16x8 b;
  uint2 u2[2];
  uint4 u4;
  u16 us[8];
};

__device__ __forceinline__ u16 f2bf(float f) {
  u32 x = __float_as_uint(f);
  x += 0x7FFFu + ((x >> 16) & 1u);
  return (u16)(x >> 16);
}
__device__ __forceinline__ float bf2f(u16 u) {
  return __uint_as_float(((u32)u) << 16);
}

// async global->LDS, 16B per lane. LDS dest = wave-uniform base + lane*16.
#define GLOAD16(gp, lp)                                                          \
  __builtin_amdgcn_global_load_lds(                                              \
      (const __attribute__((address_space(1))) unsigned int*)(const void*)(gp),  \
      (__attribute__((address_space(3))) unsigned int*)(void*)(lp), 16, 0, 0)

// ---------------- f32 -> bf16 convert: x, W_qkv, W_out in one launch ----------------
__global__ void k_convert_all(const float* __restrict__ x, const float* __restrict__ wq,
                              const float* __restrict__ wo, u16* __restrict__ xb,
                              u16* __restrict__ wqb, u16* __restrict__ wob) {
  const int NX = 1048576, NQ = 786432, NO = 262144;  // float4 counts
  int idx = blockIdx.x * blockDim.x + threadIdx.x;
  int stride = gridDim.x * blockDim.x;
  for (int i = idx; i < NX + NQ + NO; i += stride) {
    const float4* s;
    ushort4* d;
    int k;
    if (i < NX) { s = (const float4*)x; d = (ushort4*)xb; k = i; }
    else if (i < NX + NQ) { s = (const float4*)wq; d = (ushort4*)wqb; k = i - NX; }
    else { s = (const float4*)wo; d = (ushort4*)wob; k = i - NX - NQ; }
    float4 v = s[k];
    ushort4 o;
    o.x = f2bf(v.x); o.y = f2bf(v.y); o.z = f2bf(v.z); o.w = f2bf(v.w);
    d[k] = o;
  }
}

// ---------------- rel projection -> MFMA-fragment-ordered bf16 ----------------
// Fragment layout (consumed by k_attn):
//   out[tile(b,h,nt,mt)*1024 + c*256 + lane*4 + j]
//     = rel(b, h, n = nt*16 + 4*(lane>>4) + j, m = mt*64 + c*16 + (lane&15))
//   tile = ((b*16+h)*32 + nt)*8 + mt.
// One (n,m) point per thread; W/b read DIRECTLY from global with uniform
// indices -> compiler emits s_load (SGPR, K$) and v_fma with SGPR operand.
// (R6 read W from LDS: 128 ds_read_b128/thread = ~80 us of LDS issue, the
//  actual bottleneck. Scalar W removes all of it.)
__global__ __launch_bounds__(256) void k_rel(const float* __restrict__ rb,
                                             const float* __restrict__ Wr,
                                             const float* __restrict__ br,
                                             u16* __restrict__ out) {
  const int t = threadIdx.x;
  const int i16 = t & 15, j = (t >> 4) & 3, c = t >> 6;
  const int mt = blockIdx.x, ntg = blockIdx.y, b = blockIdx.z;
  const int nt = ntg >> 2, g = ntg & 3;
  const int n = nt * 16 + 4 * g + j;
  const int m = mt * 64 + c * 16 + i16;

  const float4* rp = (const float4*)(rb + ((size_t)(b * 512 + n) * 512 + m) * 32);
  float4 r4[8];
#pragma unroll
  for (int q = 0; q < 8; ++q) r4[q] = rp[q];

  const size_t obase =
      (((size_t)(b * 16) * 32 + nt) * 8 + mt) * 1024 + c * 256 + (g * 16 + i16) * 4 + j;
#pragma unroll
  for (int h = 0; h < 16; ++h) {
    float acc = br[h];
    const float* w = Wr + h * 32;
#pragma unroll
    for (int q = 0; q < 8; ++q) {
      acc += r4[q].x * w[4 * q + 0] + r4[q].y * w[4 * q + 1] +
             r4[q].z * w[4 * q + 2] + r4[q].w * w[4 * q + 3];
    }
    out[obase + (size_t)h * 262144] = f2bf(acc);
  }
}

// ---------------- GEMM: C(M x N) = A(M x K) * W(N x K)^T + bias ----------------
// m97-style: 128x128 tile, BK=64, global_load_lds(16B) staging into linear LDS,
// both-sides XOR swizzle (global source chunk ^= r&7; ds_read chunk ^= row&7).
// MODE 0: qkv -> scatter bf16 into Q,K [b][h][n][d]; V written TRANSPOSED
//         [b][h][d][n] directly (4 j-values = 4 consecutive n = one uint2).
// MODE 1: out -> f32 C row-major with bias
template <int MODE>
__global__ __launch_bounds__(256) void k_gemm(const u16* __restrict__ A,
                                              const u16* __restrict__ Bm,
                                              const float* __restrict__ bias,
                                              u16* __restrict__ Qo, u16* __restrict__ Ko,
                                              u16* __restrict__ Vo, float* __restrict__ Co,
                                              int K) {
  __shared__ u16 Al[128 * 64];
  __shared__ u16 Bl[128 * 64];
  const int t = threadIdx.x;
  const int lane = t & 63, wid = t >> 6;
  const int g = lane >> 4, i16 = lane & 15;
  const int wm = wid >> 1, wn = wid & 1;
  const int bm = blockIdx.y, bn = blockIdx.x;

  f32x4 zero = {0.f, 0.f, 0.f, 0.f};
  f32x4 acc[4][4];
#pragma unroll
  for (int mi = 0; mi < 4; ++mi)
#pragma unroll
    for (int ni = 0; ni < 4; ++ni) acc[mi][ni] = zero;

  int srow[4], sgc[4];
#pragma unroll
  for (int i = 0; i < 4; ++i) {
    int ch = wid * 256 + i * 64 + lane;
    int r = ch >> 3, cs = ch & 7;
    srow[i] = r;
    sgc[i] = cs ^ (r & 7);
  }

  for (int k0 = 0; k0 < K; k0 += 64) {
    __syncthreads();
#pragma unroll
    for (int i = 0; i < 4; ++i) {
      const u16* ga = A + (size_t)(bm * 128 + srow[i]) * K + k0 + sgc[i] * 8;
      const u16* gb = Bm + (size_t)(bn * 128 + srow[i]) * K + k0 + sgc[i] * 8;
      GLOAD16(ga, Al + (size_t)(wid * 256 + i * 64) * 8);
      GLOAD16(gb, Bl + (size_t)(wid * 256 + i * 64) * 8);
    }
    __syncthreads();

#pragma unroll
    for (int kk = 0; kk < 2; ++kk) {
      U8 af[4], bfr[4];
#pragma unroll
      for (int mi = 0; mi < 4; ++mi) {
        int row = wm * 64 + mi * 16 + i16;
        int ch = (g + 4 * kk) ^ (row & 7);
        af[mi].u4 = *(const uint4*)(Al + row * 64 + ch * 8);
      }
#pragma unroll
      for (int ni = 0; ni < 4; ++ni) {
        int row = wn * 64 + ni * 16 + i16;
        int ch = (g + 4 * kk) ^ (row & 7);
        bfr[ni].u4 = *(const uint4*)(Bl + row * 64 + ch * 8);
      }
#pragma unroll
      for (int mi = 0; mi < 4; ++mi)
#pragma unroll
        for (int ni = 0; ni < 4; ++ni)
          acc[mi][ni] = __builtin_amdgcn_mfma_f32_16x16x32_bf16(af[mi].b, bfr[ni].b,
                                                                acc[mi][ni], 0, 0, 0);
    }
  }

#pragma unroll
  for (int mi = 0; mi < 4; ++mi) {
#pragma unroll
    for (int ni = 0; ni < 4; ++ni) {
      int col = bn * 128 + wn * 64 + ni * 16 + i16;
      int row0 = bm * 128 + wm * 64 + mi * 16 + 4 * g;
      float bia = bias[col];
      if (MODE == 0) {
        int tt = col >> 10;
        int h = (col >> 6) & 15;
        int d = col & 63;
        int b = row0 >> 9;
        int n0 = row0 & 511;  // n0..n0+3 stay within this (b,h)
        if (tt < 2) {
          u16* dst = (tt == 0) ? Qo : Ko;
#pragma unroll
          for (int j = 0; j < 4; ++j)
            dst[((size_t)(b * 16 + h) * 512 + n0 + j) * 64 + d] = f2bf(acc[mi][ni][j] + bia);
        } else {
          uint2 w;
          w.x = (u32)f2bf(acc[mi][ni][0] + bia) | ((u32)f2bf(acc[mi][ni][1] + bia) << 16);
          w.y = (u32)f2bf(acc[mi][ni][2] + bia) | ((u32)f2bf(acc[mi][ni][3] + bia) << 16);
          *(uint2*)(Vo + ((size_t)(b * 16 + h) * 64 + d) * 512 + n0) = w;
        }
      } else {
#pragma unroll
        for (int j = 0; j < 4; ++j)
          Co[(size_t)(row0 + j) * 1024 + col] = acc[mi][ni][j] + bia;
      }
    }
  }
}

// ---------------- fused attention: softmax(Q K^T * scale + rel) V ----------------
// grid (qt=8, h=16, b=8), 256 threads = 4 waves, each wave owns 16 q-rows.
// K/Vt double-buffered via global_load_lds, prefetch issued before compute.
// rel read as 4x uint2 per thread per tile (dense fragment-ordered layout).
__global__ __launch_bounds__(256) void k_attn(const u16* __restrict__ Q,
                                              const u16* __restrict__ Kb,
                                              const u16* __restrict__ Vtb,
                                              const u16* __restrict__ Rel,
                                              u16* __restrict__ Out) {
  __shared__ u16 Kl[2][64 * 64];
  __shared__ u16 Vl[2][64 * 64];
  __shared__ u16 Pl[4][16 * 68];

  const int qt = blockIdx.x, h = blockIdx.y, b = blockIdx.z;
  const int t = threadIdx.x, lane = t & 63, wid = t >> 6;
  const int g = lane >> 4, i16 = lane & 15;
  const size_t bh = (size_t)(b * 16 + h);

  // Q fragments (held in registers for entire kernel)
  const u16* Qg = Q + (bh * 512 + qt * 64 + wid * 16 + i16) * 64;
  U8 qf[2];
  qf[0].u4 = *(const uint4*)(Qg + 8 * g);
  qf[1].u4 = *(const uint4*)(Qg + 8 * g + 32);

  float m_run[4], l_run[4];
  f32x4 zero = {0.f, 0.f, 0.f, 0.f};
  f32x4 acc[4];
#pragma unroll
  for (int c = 0; c < 4; ++c) acc[c] = zero;
#pragma unroll
  for (int j = 0; j < 4; ++j) { m_run[j] = -1e30f; l_run[j] = 0.f; }

  int srow[2], sgc[2];
#pragma unroll
  for (int i = 0; i < 2; ++i) {
    int ch = wid * 128 + i * 64 + lane;
    int r = ch >> 3, cs = ch & 7;
    srow[i] = r;
    sgc[i] = cs ^ (r & 7);
  }

  const u16* Kg0 = Kb + bh * 512 * 64;
  const u16* Vg0 = Vtb + bh * 64 * 512;
  // fragment-ordered rel: tile(b,h, nt=qt*4+wid, mt=it)*1024 + c*256 + lane*4 + j
  const u16* Rg = Rel + ((bh * 32 + qt * 4 + wid) * 8) * 1024 + lane * 4;

#define STAGE(buf, m0)                                                                  \
  do {                                                                                  \
    _Pragma("unroll") for (int i = 0; i < 2; ++i) {                                     \
      GLOAD16(Kg0 + (size_t)((m0) + srow[i]) * 64 + sgc[i] * 8,                         \
              &Kl[buf][(size_t)(wid * 128 + i * 64) * 8]);                              \
      GLOAD16(Vg0 + (size_t)srow[i] * 512 + (m0) + sgc[i] * 8,                          \
              &Vl[buf][(size_t)(wid * 128 + i * 64) * 8]);                              \
    }                                                                                   \
  } while (0)

  STAGE(0, 0);
  __syncthreads();

  for (int it = 0; it < 8; ++it) {
    const int buf = it & 1;
    if (it < 7) STAGE(buf ^ 1, it * 64 + 64);

    // rel fragments: 4 x uint2 (dense per wave), in flight under QK^T
    uint2 rl[4];
#pragma unroll
    for (int c = 0; c < 4; ++c) rl[c] = *(const uint2*)(Rg + it * 1024 + c * 256);

    // S = Q K^T  (per wave: 16 x 64)
    f32x4 s[4];
#pragma unroll
    for (int c = 0; c < 4; ++c) s[c] = zero;
    __builtin_amdgcn_s_setprio(1);
#pragma unroll
    for (int c = 0; c < 4; ++c) {
#pragma unroll
      for (int kk = 0; kk < 2; ++kk) {
        int row = c * 16 + i16;
        int ch = (g + 4 * kk) ^ (row & 7);
        U8 kf;
        kf.u4 = *(const uint4*)(&Kl[buf][row * 64 + ch * 8]);
        s[c] = __builtin_amdgcn_mfma_f32_16x16x32_bf16(qf[kk].b, kf.b, s[c], 0, 0, 0);
      }
    }
    __builtin_amdgcn_s_setprio(0);

    // scale + rel bias
#pragma unroll
    for (int c = 0; c < 4; ++c) {
      const u16* rc = (const u16*)&rl[c];
#pragma unroll
      for (int j = 0; j < 4; ++j) s[c][j] = s[c][j] * 0.125f + bf2f(rc[j]);
    }
    // online softmax (rows live across the 16 lanes sharing g)
    float fac[4];
#pragma unroll
    for (int j = 0; j < 4; ++j) {
      float pm = fmaxf(fmaxf(s[0][j], s[1][j]), fmaxf(s[2][j], s[3][j]));
      pm = fmaxf(pm, __shfl_xor(pm, 1));
      pm = fmaxf(pm, __shfl_xor(pm, 2));
      pm = fmaxf(pm, __shfl_xor(pm, 4));
      pm = fmaxf(pm, __shfl_xor(pm, 8));
      float mnew = fmaxf(m_run[j], pm);
      fac[j] = __expf(m_run[j] - mnew);
      m_run[j] = mnew;
    }
#pragma unroll
    for (int c = 0; c < 4; ++c)
#pragma unroll
      for (int j = 0; j < 4; ++j) s[c][j] = __expf(s[c][j] - m_run[j]);
#pragma unroll
    for (int j = 0; j < 4; ++j) {
      float rs = s[0][j] + s[1][j] + s[2][j] + s[3][j];
      rs += __shfl_xor(rs, 1);
      rs += __shfl_xor(rs, 2);
      rs += __shfl_xor(rs, 4);
      rs += __shfl_xor(rs, 8);
      l_run[j] = l_run[j] * fac[j] + rs;
    }
#pragma unroll
    for (int c = 0; c < 4; ++c)
#pragma unroll
      for (int j = 0; j < 4; ++j) acc[c][j] *= fac[j];

    // write P (bf16) to per-wave LDS region
    u16* Pw = Pl[wid];
#pragma unroll
    for (int c = 0; c < 4; ++c)
#pragma unroll
      for (int j = 0; j < 4; ++j)
        Pw[(4 * g + j) * 68 + c * 16 + i16] = f2bf(s[c][j]);
    __syncthreads();

    // O += P V
    U8 pf[2];
#pragma unroll
    for (int kk = 0; kk < 2; ++kk) {
      const u16* p = Pl[wid] + i16 * 68 + 8 * g + 32 * kk;
      pf[kk].u2[0] = *(const uint2*)p;
      pf[kk].u2[1] = *(const uint2*)(p + 4);
    }
    __builtin_amdgcn_s_setprio(1);
#pragma unroll
    for (int c = 0; c < 4; ++c) {
#pragma unroll
      for (int kk = 0; kk < 2; ++kk) {
        int row = c * 16 + i16;
        int ch = (g + 4 * kk) ^ (row & 7);
        U8 vf;
        vf.u4 = *(const uint4*)(&Vl[buf][row * 64 + ch * 8]);
        acc[c] = __builtin_amdgcn_mfma_f32_16x16x32_bf16(pf[kk].b, vf.b, acc[c], 0, 0, 0);
      }
    }
    __builtin_amdgcn_s_setprio(0);
    __syncthreads();  // protects Pl + K/V buf for next iter; drains prefetch
  }
#undef STAGE

  // epilogue: normalize, write bf16 [b][n][h*64+d]
#pragma unroll
  for (int c = 0; c < 4; ++c) {
#pragma unroll
    for (int j = 0; j < 4; ++j) {
      int n = qt * 64 + wid * 16 + 4 * g + j;
      float v = acc[c][j] / l_run[j];
      Out[((size_t)b * 512 + n) * 1024 + h * 64 + c * 16 + i16] = f2bf(v);
    }
  }
}

// ---------------- launcher ----------------
extern "C" void kernel_launch(void* const* d_in, const int* in_sizes, int n_in,
                              void* d_out, int out_size, void* d_ws, size_t ws_size,
                              hipStream_t stream) {
  const float* x = (const float*)d_in[0];
  const float* rel_bias = (const float*)d_in[1];
  const float* W_qkv = (const float*)d_in[2];
  const float* b_qkv = (const float*)d_in[3];
  const float* W_rel = (const float*)d_in[4];
  const float* b_rel = (const float*)d_in[5];
  const float* W_out = (const float*)d_in[6];
  const float* b_out = (const float*)d_in[7];
  float* out = (float*)d_out;

  char* ws = (char*)d_ws;
  u16* x_bf    = (u16*)(ws);               //  8 MB  (4096x1024)
  u16* wqkv_bf = (u16*)(ws + 8388608);     //  6 MB  (3072x1024)
  u16* wout_bf = (u16*)(ws + 14680064);    //  2 MB  (1024x1024)
  u16* Qw      = (u16*)(ws + 16777216);    //  8 MB  [b][h][n][d]
  u16* Kw      = (u16*)(ws + 25165824);    //  8 MB  [b][h][n][d]
  u16* Vt      = (u16*)(ws + 33554432);    //  8 MB  [b][h][d][n] (written by gemm<0>)
  u16* relb    = (u16*)(ws + 41943040);    // 64 MB  fragment-ordered rel
  u16* attno   = (u16*)(ws + 109051904);   //  8 MB  (4096x1024)

  k_convert_all<<<2048, 256, 0, stream>>>(x, W_qkv, W_out, x_bf, wqkv_bf, wout_bf);

  k_rel<<<dim3(8, 128, 8), 256, 0, stream>>>(rel_bias, W_rel, b_rel, relb);

  k_gemm<0><<<dim3(24, 32), 256, 0, stream>>>(x_bf, wqkv_bf, b_qkv, Qw, Kw, Vt, nullptr, 1024);

  k_attn<<<dim3(8, 16, 8), 256, 0, stream>>>(Qw, Kw, Vt, relb, attno);

  k_gemm<1><<<dim3(8, 32), 256, 0, stream>>>(attno, wout_bf, b_out, nullptr, nullptr, nullptr,
                                             out, 1024);
}